// Round 2
// baseline (631.294 us; speedup 1.0000x reference)
//
#include <hip/hip_runtime.h>
#include <math.h>

// dims
#define RN   16      // rims
#define CN   64      // channels
#define HDN  4       // heads
#define DN   16      // depth
#define KN   4       // top-k
#define HWN  4096    // 64*64 pixels per image
#define NPIX 32768   // B*H*W
#define OCN  1024    // R*HD*D
#define CHW  (CN*HWN)

// One block = 64 pixels, 512 threads (8 waves). 512 blocks -> 4096 waves (50% occ cap).
// P0: q + per-(rim,head) active-row compaction (branch-free pipelineable P1 loop)
// P1: scores, wave w handles rims {2w, 2w+1} (rows wave-uniform -> scalar loads)
// P2: top-4 + rim binning   P3: 2 threads/entry val+merge, shfl-pair reduce + LDS atomic
// P4: Wo projection, 8 channels per wave.
__global__ __launch_bounds__(512, 4) void rims_fused(
    const float* __restrict__ x,   const float* __restrict__ rims,
    const float* __restrict__ Wk,  const float* __restrict__ bk,
    const float* __restrict__ Wv,  const float* __restrict__ bv,
    const float* __restrict__ Wq,  const float* __restrict__ bq,
    const float* __restrict__ Wm,  const float* __restrict__ bm,
    const float* __restrict__ Wo,  const float* __restrict__ bo,
    float* __restrict__ out)
{
  __shared__ float q_s[OCN];          // 4 KB
  __shared__ float ipn_s[64];         // null-branch logits per (r,h)
  __shared__ float act_qv[64][16];    // 4 KB  compacted qv per (r,h)
  __shared__ int   act_o[64][16];     // 4 KB  compacted row index per (r,h)
  __shared__ int   act_cnt[64];
  __shared__ float sc_s[16 * 65];     // 4.2 KB scores [r][pix]
  __shared__ float macc_s[64 * 65];   // 16.6 KB merged accum [pix][c]
  __shared__ int   bcnt[16];
  __shared__ int   bpos[16];
  __shared__ unsigned char brim[256];
  __shared__ unsigned char bpix[256];

  const int tid   = threadIdx.x;
  const int tile  = blockIdx.x;          // 0..511
  const int b     = tile >> 6;
  const int pbase = (tile & 63) * 64;
  const float* xbase = x + (size_t)b * CHW + pbase;

  const int pl = tid & 63;
  const int wv = tid >> 6;               // wave id 0..7

  // hoist the P1 x-tile loads so they are in flight during P0
  float xv[CN];
  {
    const float* xp = xbase + pl;
    #pragma unroll
    for (int c = 0; c < CN; ++c) xv[c] = xp[c * HWN];
  }

  // ---- P0: q = relu(Wq.rims + bq); compact active rows; ip_null ----
  for (int o = tid; o < OCN; o += 512) {
    const int r = o >> 6;
    const float* wq = Wq + o * CN;
    const float* rp = rims + r * CN;
    float a0 = bq[o], a1 = 0.f, a2 = 0.f, a3 = 0.f;
    #pragma unroll
    for (int c = 0; c < CN; c += 4) {
      a0 = fmaf(wq[c+0], rp[c+0], a0);
      a1 = fmaf(wq[c+1], rp[c+1], a1);
      a2 = fmaf(wq[c+2], rp[c+2], a2);
      a3 = fmaf(wq[c+3], rp[c+3], a3);
    }
    q_s[o] = fmaxf((a0 + a1) + (a2 + a3), 0.f);
  }
  __syncthreads();
  if (tid < 64) {                        // one thread per (rim,head)
    int cnt = 0; float acc = 0.f;
    #pragma unroll
    for (int d = 0; d < DN; ++d) {
      const int o = tid * DN + d;
      const float qv = q_s[o];
      acc = fmaf(fmaxf(bk[o], 0.f), qv, acc);
      if (qv != 0.f) { act_o[tid][cnt] = o; act_qv[tid][cnt] = qv; ++cnt; }
    }
    ipn_s[tid]   = acc;
    act_cnt[tid] = cnt;
  }
  __syncthreads();

  // ---- P1: scores. wave wv -> rims {2wv, 2wv+1}; branch-free compacted rows ----
  #pragma unroll 1
  for (int rr = 0; rr < 2; ++rr) {
    const int r = wv * 2 + rr;
    float score = 0.f;
    #pragma unroll 1
    for (int h = 0; h < HDN; ++h) {
      const int rh  = r * HDN + h;
      const int cnt = __builtin_amdgcn_readfirstlane(act_cnt[rh]);
      const float ipn = ipn_s[rh];
      float ip = 0.f;
      #pragma unroll 2
      for (int i = 0; i < cnt; ++i) {
        const int   o  = __builtin_amdgcn_readfirstlane(act_o[rh][i]);
        const float qv = act_qv[rh][i];
        const float* w = Wk + o * CN;     // wave-uniform row -> scalar loads
        float a0 = bk[o], a1 = 0.f, a2 = 0.f, a3 = 0.f;
        #pragma unroll
        for (int c = 0; c < CN; c += 4) {
          a0 = fmaf(w[c+0], xv[c+0], a0);
          a1 = fmaf(w[c+1], xv[c+1], a1);
          a2 = fmaf(w[c+2], xv[c+2], a2);
          a3 = fmaf(w[c+3], xv[c+3], a3);
        }
        ip = fmaf(fmaxf((a0 + a1) + (a2 + a3), 0.f), qv, ip);
      }
      score += 1.f / (1.f + expf(ipn - ip));   // sigmoid(ip - ipn)
    }
    sc_s[r * 65 + pl] = score;
  }
  __syncthreads();

  // ---- P2: zero accum, top-4, rim binning ----
  for (int i = tid; i < 64 * 65; i += 512) macc_s[i] = 0.f;
  if (tid < 16) bcnt[tid] = 0;
  __syncthreads();

  int rs0 = 0, rs1 = 0, rs2 = 0, rs3 = 0;
  if (tid < 64) {
    float s[RN];
    #pragma unroll
    for (int r = 0; r < RN; ++r) s[r] = sc_s[r * 65 + tid];
    #pragma unroll
    for (int k = 0; k < KN; ++k) {   // strict > == lowest-index-first tie order
      float best = -3.4e38f; int bi = 0;
      #pragma unroll
      for (int r = 0; r < RN; ++r) { if (s[r] > best) { best = s[r]; bi = r; } }
      if (k == 0) rs0 = bi; else if (k == 1) rs1 = bi;
      else if (k == 2) rs2 = bi; else rs3 = bi;
      s[bi] = -3.4e38f;
    }
    atomicAdd(&bcnt[rs0], 1); atomicAdd(&bcnt[rs1], 1);
    atomicAdd(&bcnt[rs2], 1); atomicAdd(&bcnt[rs3], 1);
  }
  __syncthreads();
  if (tid == 0) {
    int run = 0;
    #pragma unroll
    for (int r = 0; r < RN; ++r) { bpos[r] = run; run += bcnt[r]; }
  }
  __syncthreads();
  if (tid < 64) {
    int p0 = atomicAdd(&bpos[rs0], 1); brim[p0] = (unsigned char)rs0; bpix[p0] = (unsigned char)tid;
    int p1 = atomicAdd(&bpos[rs1], 1); brim[p1] = (unsigned char)rs1; bpix[p1] = (unsigned char)tid;
    int p2 = atomicAdd(&bpos[rs2], 1); brim[p2] = (unsigned char)rs2; bpix[p2] = (unsigned char)tid;
    int p3 = atomicAdd(&bpos[rs3], 1); brim[p3] = (unsigned char)rs3; bpix[p3] = (unsigned char)tid;
  }
  __syncthreads();

  // ---- P3: 2 threads per binned entry (d-halves); shfl-pair reduce + atomic ----
  {
    const int e    = tid >> 1;
    const int half = tid & 1;
    const int rim  = (int)brim[e];
    const int pp   = (int)bpix[e];
    const float* xp = xbase + pp;
    float xw[CN];
    #pragma unroll
    for (int c = 0; c < CN; ++c) xw[c] = xp[c * HWN];

    float vald[32];
    const float* wvb = Wv + (size_t)(rim * CN + half * 32) * CN;
    const float* bvp = bv + rim * CN + half * 32;
    #pragma unroll 4
    for (int d = 0; d < 32; ++d) {
      const float4* w4 = (const float4*)(wvb + d * CN);
      float a0 = bvp[d], a1 = 0.f, a2 = 0.f, a3 = 0.f;
      #pragma unroll
      for (int c4 = 0; c4 < 16; ++c4) {
        const float4 wq = w4[c4];
        a0 = fmaf(wq.x, xw[c4*4+0], a0);
        a1 = fmaf(wq.y, xw[c4*4+1], a1);
        a2 = fmaf(wq.z, xw[c4*4+2], a2);
        a3 = fmaf(wq.w, xw[c4*4+3], a3);
      }
      vald[d] = fmaxf((a0 + a1) + (a2 + a3), 0.f);
    }

    const float* wmb = Wm + (size_t)rim * CN * 64 + half * 32;  // Wm[r][c][64]
    const float* bmp = bm + rim * CN;
    #pragma unroll 2
    for (int c = 0; c < CN; ++c) {
      const float4* w4 = (const float4*)(wmb + c * 64);
      float m0 = (half == 0) ? bmp[c] : 0.f;
      float m1 = 0.f, m2 = 0.f, m3 = 0.f;
      #pragma unroll
      for (int k4 = 0; k4 < 8; ++k4) {
        const float4 wq = w4[k4];
        m0 = fmaf(wq.x, vald[k4*4+0], m0);
        m1 = fmaf(wq.y, vald[k4*4+1], m1);
        m2 = fmaf(wq.z, vald[k4*4+2], m2);
        m3 = fmaf(wq.w, vald[k4*4+3], m3);
      }
      float m = (m0 + m1) + (m2 + m3);
      m += __shfl_xor(m, 1);                 // pair-reduce the two d-halves
      if ((c >> 5) == half)                  // each lane commits its c-half
        atomicAdd(&macc_s[pp * 65 + c], m);
    }
  }
  __syncthreads();

  // ---- P4: u = relu(mean); out = relu(Wo u + bo). 8 channels per wave ----
  {
    float u[CN];
    #pragma unroll
    for (int c = 0; c < CN; ++c)
      u[c] = fmaxf(macc_s[pl * 65 + c] * 0.25f, 0.f);
    float* op = out + (size_t)b * CHW + pbase + pl;
    #pragma unroll 1
    for (int t = 0; t < 8; ++t) {
      const int co = wv * 8 + t;
      const float* w = Wo + co * CN;         // wave-uniform -> scalar loads
      float a0 = bo[co], a1 = 0.f, a2 = 0.f, a3 = 0.f;
      #pragma unroll
      for (int c = 0; c < CN; c += 4) {
        a0 = fmaf(w[c+0], u[c+0], a0);
        a1 = fmaf(w[c+1], u[c+1], a1);
        a2 = fmaf(w[c+2], u[c+2], a2);
        a3 = fmaf(w[c+3], u[c+3], a3);
      }
      op[co * HWN] = fmaxf((a0 + a1) + (a2 + a3), 0.f);
    }
  }
}

extern "C" void kernel_launch(void* const* d_in, const int* in_sizes, int n_in,
                              void* d_out, int out_size, void* d_ws, size_t ws_size,
                              hipStream_t stream) {
  (void)in_sizes; (void)n_in; (void)d_ws; (void)ws_size; (void)out_size;
  const float* xx   = (const float*)d_in[0];
  const float* rims = (const float*)d_in[1];
  const float* Wk   = (const float*)d_in[2];
  const float* bk   = (const float*)d_in[3];
  const float* Wv   = (const float*)d_in[4];
  const float* bv   = (const float*)d_in[5];
  const float* Wq   = (const float*)d_in[6];
  const float* bq   = (const float*)d_in[7];
  const float* Wm   = (const float*)d_in[8];
  const float* bm   = (const float*)d_in[9];
  const float* Wo   = (const float*)d_in[10];
  const float* bo   = (const float*)d_in[11];
  float* outp = (float*)d_out;

  rims_fused<<<dim3(NPIX / 64), dim3(512), 0, stream>>>(
      xx, rims, Wk, bk, Wv, bv, Wq, bq, Wm, bm, Wo, bo, outp);
}

// Round 3
// 626.579 us; speedup vs baseline: 1.0075x; 1.0075x over previous
//
#include <hip/hip_runtime.h>
#include <math.h>

// dims
#define RN   16      // rims
#define CN   64      // channels
#define HDN  4       // heads
#define DN   16      // depth
#define KN   4       // top-k
#define HWN  4096    // 64*64 pixels per image
#define NPIX 32768   // B*H*W
#define OCN  1024    // R*HD*D
#define CHW  (CN*HWN)

// ---------------- K1: scores ----------------
// 1024 blocks = 512 (64-pixel tiles) x 2 (rim halves). 256 threads, 4 waves.
// Wave wv handles rims {half*8 + 2wv, half*8 + 2wv + 1} sequentially; lanes = pixels.
// Weight rows are wave-uniform (readfirstlane) -> scalar loads, branch-free
// compacted active-row list (qv != 0) for software pipelining.
__global__ __launch_bounds__(256, 4) void k_scores(
    const float* __restrict__ x,   const float* __restrict__ rims,
    const float* __restrict__ Wk,  const float* __restrict__ bk,
    const float* __restrict__ Wq,  const float* __restrict__ bq,
    float* __restrict__ sc)                       // [16][32768]
{
  __shared__ float q_s[OCN];        // 4 KB (full q; only half's rows used)
  __shared__ float ipn_s[32];       // null logits for this half's (r,h)
  __shared__ float act_qv[32][16];  // compacted qv
  __shared__ int   act_o[32][16];   // compacted row index
  __shared__ int   act_cnt[32];

  const int tid  = threadIdx.x;
  const int blk  = blockIdx.x;        // 0..1023
  const int T    = blk >> 1;          // 64-pixel tile 0..511
  const int half = blk & 1;           // rim half
  const int b     = T >> 6;
  const int pbase = (T & 63) * 64;
  const float* xbase = x + (size_t)b * CHW + pbase;

  const int pl = tid & 63;
  const int wv = tid >> 6;            // 0..3

  // hoist x-tile loads; in flight during P0
  float xv[CN];
  {
    const float* xp = xbase + pl;
    #pragma unroll
    for (int c = 0; c < CN; ++c) xv[c] = xp[c * HWN];
  }

  // ---- P0: q rows for this half (512 rows); compaction + ip_null ----
  for (int i = 0; i < 2; ++i) {
    const int o = half * 512 + i * 256 + tid;
    const int r = o >> 6;
    const float* wq = Wq + o * CN;
    const float* rp = rims + r * CN;
    float a0 = bq[o], a1 = 0.f, a2 = 0.f, a3 = 0.f;
    #pragma unroll
    for (int c = 0; c < CN; c += 4) {
      a0 = fmaf(wq[c+0], rp[c+0], a0);
      a1 = fmaf(wq[c+1], rp[c+1], a1);
      a2 = fmaf(wq[c+2], rp[c+2], a2);
      a3 = fmaf(wq[c+3], rp[c+3], a3);
    }
    q_s[o] = fmaxf((a0 + a1) + (a2 + a3), 0.f);
  }
  __syncthreads();
  if (tid < 32) {                       // one thread per (rim,head) of this half
    const int rh = half * 32 + tid;     // global rh
    int cnt = 0; float acc = 0.f;
    #pragma unroll
    for (int d = 0; d < DN; ++d) {
      const int o = rh * DN + d;
      const float qv = q_s[o];
      acc = fmaf(fmaxf(bk[o], 0.f), qv, acc);
      if (qv != 0.f) { act_o[tid][cnt] = o; act_qv[tid][cnt] = qv; ++cnt; }
    }
    ipn_s[tid]   = acc;
    act_cnt[tid] = cnt;
  }
  __syncthreads();

  // ---- P1: scores for 2 rims per wave ----
  #pragma unroll 1
  for (int rr = 0; rr < 2; ++rr) {
    const int rl = wv * 2 + rr;          // rim-local 0..7
    const int r  = half * 8 + rl;        // global rim
    float score = 0.f;
    #pragma unroll 1
    for (int h = 0; h < HDN; ++h) {
      const int rhl = rl * HDN + h;      // local (r,h) 0..31
      const int cnt = __builtin_amdgcn_readfirstlane(act_cnt[rhl]);
      const float ipn = ipn_s[rhl];
      float ip = 0.f;
      #pragma unroll 2
      for (int i = 0; i < cnt; ++i) {
        const int   o  = __builtin_amdgcn_readfirstlane(act_o[rhl][i]);
        const float qv = act_qv[rhl][i];
        const float* w = Wk + o * CN;    // wave-uniform -> s_load
        float a0 = bk[o], a1 = 0.f, a2 = 0.f, a3 = 0.f;
        #pragma unroll
        for (int c = 0; c < CN; c += 4) {
          a0 = fmaf(w[c+0], xv[c+0], a0);
          a1 = fmaf(w[c+1], xv[c+1], a1);
          a2 = fmaf(w[c+2], xv[c+2], a2);
          a3 = fmaf(w[c+3], xv[c+3], a3);
        }
        ip = fmaf(fmaxf((a0 + a1) + (a2 + a3), 0.f), qv, ip);
      }
      score += 1.f / (1.f + expf(ipn - ip));   // sigmoid(ip - ipn)
    }
    sc[r * NPIX + T * 64 + pl] = score;        // coalesced 256B store
  }
}

// ---------------- K2: select + val/merge + Wo ----------------
// 1024 blocks = 32-pixel tiles. 256 threads.
// top-4 from ws, rim binning (128 entries), 2 threads/entry d-half split with
// shfl pair-reduce + LDS fp32 atomics, then Wo (8 channels/thread-group).
__global__ __launch_bounds__(256, 4) void k_merge(
    const float* __restrict__ x,   const float* __restrict__ sc,
    const float* __restrict__ Wv,  const float* __restrict__ bv,
    const float* __restrict__ Wm,  const float* __restrict__ bm,
    const float* __restrict__ Wo,  const float* __restrict__ bo,
    float* __restrict__ out)
{
  __shared__ float macc_s[32 * 65];   // 8.3 KB merged accum [pix][c]
  __shared__ int   bcnt[16];
  __shared__ int   bpos[16];
  __shared__ unsigned char brim[128];
  __shared__ unsigned char bpix[128];

  const int tid = threadIdx.x;
  const int t2  = blockIdx.x;          // 0..1023
  const int b      = t2 >> 7;
  const int hwbase = (t2 & 127) * 32;
  const int pglob  = t2 * 32;          // global pixel base
  const float* xbase = x + (size_t)b * CHW + hwbase;

  for (int i = tid; i < 32 * 65; i += 256) macc_s[i] = 0.f;
  if (tid < 16) bcnt[tid] = 0;
  __syncthreads();

  int rs0 = 0, rs1 = 0, rs2 = 0, rs3 = 0;
  if (tid < 32) {
    float s[RN];
    #pragma unroll
    for (int r = 0; r < RN; ++r) s[r] = sc[r * NPIX + pglob + tid];
    #pragma unroll
    for (int k = 0; k < KN; ++k) {     // strict > == lowest-index tie order
      float best = -3.4e38f; int bi = 0;
      #pragma unroll
      for (int r = 0; r < RN; ++r) { if (s[r] > best) { best = s[r]; bi = r; } }
      if (k == 0) rs0 = bi; else if (k == 1) rs1 = bi;
      else if (k == 2) rs2 = bi; else rs3 = bi;
      s[bi] = -3.4e38f;
    }
    atomicAdd(&bcnt[rs0], 1); atomicAdd(&bcnt[rs1], 1);
    atomicAdd(&bcnt[rs2], 1); atomicAdd(&bcnt[rs3], 1);
  }
  __syncthreads();
  if (tid == 0) {
    int run = 0;
    #pragma unroll
    for (int r = 0; r < RN; ++r) { bpos[r] = run; run += bcnt[r]; }
  }
  __syncthreads();
  if (tid < 32) {
    int p0 = atomicAdd(&bpos[rs0], 1); brim[p0] = (unsigned char)rs0; bpix[p0] = (unsigned char)tid;
    int p1 = atomicAdd(&bpos[rs1], 1); brim[p1] = (unsigned char)rs1; bpix[p1] = (unsigned char)tid;
    int p2 = atomicAdd(&bpos[rs2], 1); brim[p2] = (unsigned char)rs2; bpix[p2] = (unsigned char)tid;
    int p3 = atomicAdd(&bpos[rs3], 1); brim[p3] = (unsigned char)rs3; bpix[p3] = (unsigned char)tid;
  }
  __syncthreads();

  // ---- P3: 2 threads per binned entry (d-halves) ----
  {
    const int e    = tid >> 1;
    const int half = tid & 1;
    const int rim  = (int)brim[e];
    const int pp   = (int)bpix[e];
    const float* xp = xbase + pp;
    float xw[CN];
    #pragma unroll
    for (int c = 0; c < CN; ++c) xw[c] = xp[c * HWN];

    float vald[32];
    const float* wvb = Wv + (size_t)(rim * CN + half * 32) * CN;
    const float* bvp = bv + rim * CN + half * 32;
    #pragma unroll 4
    for (int d = 0; d < 32; ++d) {
      const float4* w4 = (const float4*)(wvb + d * CN);
      float a0 = bvp[d], a1 = 0.f, a2 = 0.f, a3 = 0.f;
      #pragma unroll
      for (int c4 = 0; c4 < 16; ++c4) {
        const float4 wq = w4[c4];
        a0 = fmaf(wq.x, xw[c4*4+0], a0);
        a1 = fmaf(wq.y, xw[c4*4+1], a1);
        a2 = fmaf(wq.z, xw[c4*4+2], a2);
        a3 = fmaf(wq.w, xw[c4*4+3], a3);
      }
      vald[d] = fmaxf((a0 + a1) + (a2 + a3), 0.f);
    }

    const float* wmb = Wm + (size_t)rim * CN * 64 + half * 32;  // Wm[r][c][64]
    const float* bmp = bm + rim * CN;
    #pragma unroll 2
    for (int c = 0; c < CN; ++c) {
      const float4* w4 = (const float4*)(wmb + c * 64);
      float m0 = (half == 0) ? bmp[c] : 0.f;
      float m1 = 0.f, m2 = 0.f, m3 = 0.f;
      #pragma unroll
      for (int k4 = 0; k4 < 8; ++k4) {
        const float4 wq = w4[k4];
        m0 = fmaf(wq.x, vald[k4*4+0], m0);
        m1 = fmaf(wq.y, vald[k4*4+1], m1);
        m2 = fmaf(wq.z, vald[k4*4+2], m2);
        m3 = fmaf(wq.w, vald[k4*4+3], m3);
      }
      float m = (m0 + m1) + (m2 + m3);
      m += __shfl_xor(m, 1);             // pair-reduce d-halves
      if ((c >> 5) == half)              // each lane commits its c-half
        atomicAdd(&macc_s[pp * 65 + c], m);
    }
  }
  __syncthreads();

  // ---- P4: u = relu(mean); out = relu(Wo u + bo). 8 out-ch per thread ----
  {
    const int pl  = tid & 31;
    const int grp = tid >> 5;            // 0..7
    float u[CN];
    #pragma unroll
    for (int c = 0; c < CN; ++c)
      u[c] = fmaxf(macc_s[pl * 65 + c] * 0.25f, 0.f);
    float* op = out + (size_t)b * CHW + hwbase + pl;
    #pragma unroll 1
    for (int t = 0; t < 8; ++t) {
      const int co = grp * 8 + t;
      const float* w = Wo + co * CN;     // 2 distinct rows per wave
      float a0 = bo[co], a1 = 0.f, a2 = 0.f, a3 = 0.f;
      #pragma unroll
      for (int c = 0; c < CN; c += 4) {
        a0 = fmaf(w[c+0], u[c+0], a0);
        a1 = fmaf(w[c+1], u[c+1], a1);
        a2 = fmaf(w[c+2], u[c+2], a2);
        a3 = fmaf(w[c+3], u[c+3], a3);
      }
      op[co * HWN] = fmaxf((a0 + a1) + (a2 + a3), 0.f);
    }
  }
}

extern "C" void kernel_launch(void* const* d_in, const int* in_sizes, int n_in,
                              void* d_out, int out_size, void* d_ws, size_t ws_size,
                              hipStream_t stream) {
  (void)in_sizes; (void)n_in; (void)ws_size; (void)out_size;
  const float* xx   = (const float*)d_in[0];
  const float* rims = (const float*)d_in[1];
  const float* Wk   = (const float*)d_in[2];
  const float* bk   = (const float*)d_in[3];
  const float* Wv   = (const float*)d_in[4];
  const float* bv   = (const float*)d_in[5];
  const float* Wq   = (const float*)d_in[6];
  const float* bq   = (const float*)d_in[7];
  const float* Wm   = (const float*)d_in[8];
  const float* bm   = (const float*)d_in[9];
  const float* Wo   = (const float*)d_in[10];
  const float* bo   = (const float*)d_in[11];
  float* outp = (float*)d_out;
  float* sc   = (float*)d_ws;            // 16*32768*4 = 2 MB scratch

  k_scores<<<dim3(1024), dim3(256), 0, stream>>>(xx, rims, Wk, bk, Wq, bq, sc);
  k_merge <<<dim3(1024), dim3(256), 0, stream>>>(xx, sc, Wv, bv, Wm, bm, Wo, bo, outp);
}

// Round 4
// 431.693 us; speedup vs baseline: 1.4624x; 1.4514x over previous
//
#include <hip/hip_runtime.h>
#include <math.h>

// dims
#define RN   16      // rims
#define CN   64      // channels
#define HDN  4       // heads
#define DN   16      // depth
#define KN   4       // top-k
#define HWN  4096    // 64*64 pixels per image
#define NPIX 32768   // B*H*W
#define OCN  1024    // R*HD*D
#define CHW  (CN*HWN)

// NOTE: do NOT pass a second __launch_bounds__ arg — on gfx950 it forced a
// 64-VGPR budget (R2/R3: VGPR_Count=64, ~1 GB scratch spill traffic).
// Plain (256) gives ~100 VGPR, no spill (R1), and 16 waves/CU at 4 blocks/CU.

// ---------------- K1: scores ----------------
// 1024 blocks = 512 (64-pixel tiles) x 2 (rim halves). 256 threads, 4 waves.
__global__ __launch_bounds__(256) void k_scores(
    const float* __restrict__ x,   const float* __restrict__ rims,
    const float* __restrict__ Wk,  const float* __restrict__ bk,
    const float* __restrict__ Wq,  const float* __restrict__ bq,
    float* __restrict__ sc)                       // [16][32768]
{
  __shared__ float q_s[OCN];        // 4 KB (full q; only half's rows used)
  __shared__ float ipn_s[32];       // null logits for this half's (r,h)
  __shared__ float act_qv[32][16];  // compacted qv
  __shared__ int   act_o[32][16];   // compacted row index
  __shared__ int   act_cnt[32];

  const int tid  = threadIdx.x;
  const int blk  = blockIdx.x;        // 0..1023
  const int T    = blk >> 1;          // 64-pixel tile 0..511
  const int half = blk & 1;           // rim half
  const int b     = T >> 6;
  const int pbase = (T & 63) * 64;
  const float* xbase = x + (size_t)b * CHW + pbase;

  const int pl = tid & 63;
  const int wv = tid >> 6;            // 0..3

  // hoist x-tile loads; in flight during P0
  float xv[CN];
  {
    const float* xp = xbase + pl;
    #pragma unroll
    for (int c = 0; c < CN; ++c) xv[c] = xp[c * HWN];
  }

  // ---- P0: q rows for this half (512 rows); compaction + ip_null ----
  for (int i = 0; i < 2; ++i) {
    const int o = half * 512 + i * 256 + tid;
    const int r = o >> 6;
    const float* wq = Wq + o * CN;
    const float* rp = rims + r * CN;
    float a0 = bq[o], a1 = 0.f, a2 = 0.f, a3 = 0.f;
    #pragma unroll
    for (int c = 0; c < CN; c += 4) {
      a0 = fmaf(wq[c+0], rp[c+0], a0);
      a1 = fmaf(wq[c+1], rp[c+1], a1);
      a2 = fmaf(wq[c+2], rp[c+2], a2);
      a3 = fmaf(wq[c+3], rp[c+3], a3);
    }
    q_s[o] = fmaxf((a0 + a1) + (a2 + a3), 0.f);
  }
  __syncthreads();
  if (tid < 32) {                       // one thread per (rim,head) of this half
    const int rh = half * 32 + tid;     // global rh
    int cnt = 0; float acc = 0.f;
    #pragma unroll
    for (int d = 0; d < DN; ++d) {
      const int o = rh * DN + d;
      const float qv = q_s[o];
      acc = fmaf(fmaxf(bk[o], 0.f), qv, acc);
      if (qv != 0.f) { act_o[tid][cnt] = o; act_qv[tid][cnt] = qv; ++cnt; }
    }
    ipn_s[tid]   = acc;
    act_cnt[tid] = cnt;
  }
  __syncthreads();

  // ---- P1: scores for 2 rims per wave ----
  #pragma unroll 1
  for (int rr = 0; rr < 2; ++rr) {
    const int rl = wv * 2 + rr;          // rim-local 0..7
    const int r  = half * 8 + rl;        // global rim
    float score = 0.f;
    #pragma unroll 1
    for (int h = 0; h < HDN; ++h) {
      const int rhl = rl * HDN + h;      // local (r,h) 0..31
      const int cnt = __builtin_amdgcn_readfirstlane(act_cnt[rhl]);
      const float ipn = ipn_s[rhl];
      float ip = 0.f;
      #pragma unroll 2
      for (int i = 0; i < cnt; ++i) {
        const int   o  = __builtin_amdgcn_readfirstlane(act_o[rhl][i]);
        const float qv = act_qv[rhl][i];
        const float* w = Wk + o * CN;    // wave-uniform -> s_load
        float a0 = bk[o], a1 = 0.f, a2 = 0.f, a3 = 0.f;
        #pragma unroll
        for (int c = 0; c < CN; c += 4) {
          a0 = fmaf(w[c+0], xv[c+0], a0);
          a1 = fmaf(w[c+1], xv[c+1], a1);
          a2 = fmaf(w[c+2], xv[c+2], a2);
          a3 = fmaf(w[c+3], xv[c+3], a3);
        }
        ip = fmaf(fmaxf((a0 + a1) + (a2 + a3), 0.f), qv, ip);
      }
      score += 1.f / (1.f + expf(ipn - ip));   // sigmoid(ip - ipn)
    }
    sc[r * NPIX + T * 64 + pl] = score;        // coalesced 256B store
  }
}

// ---------------- K2: select + val/merge + Wo ----------------
// 1024 blocks = 32-pixel tiles. 256 threads.
__global__ __launch_bounds__(256) void k_merge(
    const float* __restrict__ x,   const float* __restrict__ sc,
    const float* __restrict__ Wv,  const float* __restrict__ bv,
    const float* __restrict__ Wm,  const float* __restrict__ bm,
    const float* __restrict__ Wo,  const float* __restrict__ bo,
    float* __restrict__ out)
{
  __shared__ float macc_s[32 * 65];   // 8.3 KB merged accum [pix][c]
  __shared__ int   bcnt[16];
  __shared__ int   bpos[16];
  __shared__ unsigned char brim[128];
  __shared__ unsigned char bpix[128];

  const int tid = threadIdx.x;
  const int t2  = blockIdx.x;          // 0..1023
  const int b      = t2 >> 7;
  const int hwbase = (t2 & 127) * 32;
  const int pglob  = t2 * 32;          // global pixel base
  const float* xbase = x + (size_t)b * CHW + hwbase;

  for (int i = tid; i < 32 * 65; i += 256) macc_s[i] = 0.f;
  if (tid < 16) bcnt[tid] = 0;
  __syncthreads();

  int rs0 = 0, rs1 = 0, rs2 = 0, rs3 = 0;
  if (tid < 32) {
    float s[RN];
    #pragma unroll
    for (int r = 0; r < RN; ++r) s[r] = sc[r * NPIX + pglob + tid];
    #pragma unroll
    for (int k = 0; k < KN; ++k) {     // strict > == lowest-index tie order
      float best = -3.4e38f; int bi = 0;
      #pragma unroll
      for (int r = 0; r < RN; ++r) { if (s[r] > best) { best = s[r]; bi = r; } }
      if (k == 0) rs0 = bi; else if (k == 1) rs1 = bi;
      else if (k == 2) rs2 = bi; else rs3 = bi;
      s[bi] = -3.4e38f;
    }
    atomicAdd(&bcnt[rs0], 1); atomicAdd(&bcnt[rs1], 1);
    atomicAdd(&bcnt[rs2], 1); atomicAdd(&bcnt[rs3], 1);
  }
  __syncthreads();
  if (tid == 0) {
    int run = 0;
    #pragma unroll
    for (int r = 0; r < RN; ++r) { bpos[r] = run; run += bcnt[r]; }
  }
  __syncthreads();
  if (tid < 32) {
    int p0 = atomicAdd(&bpos[rs0], 1); brim[p0] = (unsigned char)rs0; bpix[p0] = (unsigned char)tid;
    int p1 = atomicAdd(&bpos[rs1], 1); brim[p1] = (unsigned char)rs1; bpix[p1] = (unsigned char)tid;
    int p2 = atomicAdd(&bpos[rs2], 1); brim[p2] = (unsigned char)rs2; bpix[p2] = (unsigned char)tid;
    int p3 = atomicAdd(&bpos[rs3], 1); brim[p3] = (unsigned char)rs3; bpix[p3] = (unsigned char)tid;
  }
  __syncthreads();

  // ---- P3: 2 threads per binned entry (d-halves); shfl pair-reduce + atomic ----
  {
    const int e    = tid >> 1;
    const int half = tid & 1;
    const int rim  = (int)brim[e];
    const int pp   = (int)bpix[e];
    const float* xp = xbase + pp;
    float xw[CN];
    #pragma unroll
    for (int c = 0; c < CN; ++c) xw[c] = xp[c * HWN];

    float vald[32];
    const float* wvb = Wv + (size_t)(rim * CN + half * 32) * CN;
    const float* bvp = bv + rim * CN + half * 32;
    #pragma unroll 4
    for (int d = 0; d < 32; ++d) {
      const float4* w4 = (const float4*)(wvb + d * CN);
      float a0 = bvp[d], a1 = 0.f, a2 = 0.f, a3 = 0.f;
      #pragma unroll
      for (int c4 = 0; c4 < 16; ++c4) {
        const float4 wq = w4[c4];
        a0 = fmaf(wq.x, xw[c4*4+0], a0);
        a1 = fmaf(wq.y, xw[c4*4+1], a1);
        a2 = fmaf(wq.z, xw[c4*4+2], a2);
        a3 = fmaf(wq.w, xw[c4*4+3], a3);
      }
      vald[d] = fmaxf((a0 + a1) + (a2 + a3), 0.f);
    }

    const float* wmb = Wm + (size_t)rim * CN * 64 + half * 32;  // Wm[r][c][64]
    const float* bmp = bm + rim * CN;
    #pragma unroll 2
    for (int c = 0; c < CN; ++c) {
      const float4* w4 = (const float4*)(wmb + c * 64);
      float m0 = (half == 0) ? bmp[c] : 0.f;
      float m1 = 0.f, m2 = 0.f, m3 = 0.f;
      #pragma unroll
      for (int k4 = 0; k4 < 8; ++k4) {
        const float4 wq = w4[k4];
        m0 = fmaf(wq.x, vald[k4*4+0], m0);
        m1 = fmaf(wq.y, vald[k4*4+1], m1);
        m2 = fmaf(wq.z, vald[k4*4+2], m2);
        m3 = fmaf(wq.w, vald[k4*4+3], m3);
      }
      float m = (m0 + m1) + (m2 + m3);
      m += __shfl_xor(m, 1);             // pair-reduce d-halves
      if ((c >> 5) == half)              // each lane commits its c-half
        atomicAdd(&macc_s[pp * 65 + c], m);
    }
  }
  __syncthreads();

  // ---- P4: u = relu(mean); out = relu(Wo u + bo). 8 out-ch per thread ----
  {
    const int pl  = tid & 31;
    const int grp = tid >> 5;            // 0..7
    float u[CN];
    #pragma unroll
    for (int c = 0; c < CN; ++c)
      u[c] = fmaxf(macc_s[pl * 65 + c] * 0.25f, 0.f);
    float* op = out + (size_t)b * CHW + hwbase + pl;
    #pragma unroll 1
    for (int t = 0; t < 8; ++t) {
      const int co = grp * 8 + t;
      const float* w = Wo + co * CN;     // 2 distinct rows per wave
      float a0 = bo[co], a1 = 0.f, a2 = 0.f, a3 = 0.f;
      #pragma unroll
      for (int c = 0; c < CN; c += 4) {
        a0 = fmaf(w[c+0], u[c+0], a0);
        a1 = fmaf(w[c+1], u[c+1], a1);
        a2 = fmaf(w[c+2], u[c+2], a2);
        a3 = fmaf(w[c+3], u[c+3], a3);
      }
      op[co * HWN] = fmaxf((a0 + a1) + (a2 + a3), 0.f);
    }
  }
}

extern "C" void kernel_launch(void* const* d_in, const int* in_sizes, int n_in,
                              void* d_out, int out_size, void* d_ws, size_t ws_size,
                              hipStream_t stream) {
  (void)in_sizes; (void)n_in; (void)ws_size; (void)out_size;
  const float* xx   = (const float*)d_in[0];
  const float* rims = (const float*)d_in[1];
  const float* Wk   = (const float*)d_in[2];
  const float* bk   = (const float*)d_in[3];
  const float* Wv   = (const float*)d_in[4];
  const float* bv   = (const float*)d_in[5];
  const float* Wq   = (const float*)d_in[6];
  const float* bq   = (const float*)d_in[7];
  const float* Wm   = (const float*)d_in[8];
  const float* bm   = (const float*)d_in[9];
  const float* Wo   = (const float*)d_in[10];
  const float* bo   = (const float*)d_in[11];
  float* outp = (float*)d_out;
  float* sc   = (float*)d_ws;            // 16*32768*4 = 2 MB scratch

  k_scores<<<dim3(1024), dim3(256), 0, stream>>>(xx, rims, Wk, bk, Wq, bq, sc);
  k_merge <<<dim3(1024), dim3(256), 0, stream>>>(xx, sc, Wv, bv, Wm, bm, Wo, bo, outp);
}